// Round 4
// baseline (726.063 us; speedup 1.0000x reference)
//
#include <hip/hip_runtime.h>
#include <hip/hip_fp16.h>
#include <math.h>

#define NNODES 50000
#define NEDGES 800000
#define ETOT   (NEDGES + NNODES)
#define HIDC   32
#define NGRAPH 64
#define NCLS   10
#define SLOPE  0.2f
#define SCAN_BLOCKS ((NNODES + 255) / 256)   // 196

__device__ __forceinline__ float lrelu(float v) { return v > 0.f ? v : SLOPE * v; }

// ---------------- CSR build (by dst), includes self loops ----------------
__global__ void hist_kernel(const int* __restrict__ ei, int* __restrict__ deg) {
  int e = blockIdx.x * 256 + threadIdx.x;
  if (e >= ETOT) return;
  int d = (e < NEDGES) ? ei[NEDGES + e] : (e - NEDGES);
  atomicAdd(&deg[d], 1);
}

__global__ __launch_bounds__(256)
void scan_block_kernel(const int* __restrict__ deg, int* __restrict__ row_start,
                       int* __restrict__ bsum) {
  __shared__ int wsum[4];
  int i = blockIdx.x * 256 + threadIdx.x;
  int v = (i < NNODES) ? deg[i] : 0;
  int lane = threadIdx.x & 63, w = threadIdx.x >> 6;
  int x = v;
  #pragma unroll
  for (int d = 1; d < 64; d <<= 1) {
    int y = __shfl_up(x, d);
    if (lane >= d) x += y;
  }
  if (lane == 63) wsum[w] = x;
  __syncthreads();
  int woff = 0;
  #pragma unroll
  for (int j = 0; j < 4; ++j) if (j < w) woff += wsum[j];
  int incl = x + woff;
  if (i < NNODES) row_start[i] = incl - v;
  if (threadIdx.x == 255) bsum[blockIdx.x] = incl;
}

__global__ __launch_bounds__(256)
void scan_sums_kernel(const int* __restrict__ bsum, int* __restrict__ boff) {
  __shared__ int wsum[4];
  int tid = threadIdx.x;
  int v = (tid < SCAN_BLOCKS) ? bsum[tid] : 0;
  int lane = tid & 63, w = tid >> 6;
  int x = v;
  #pragma unroll
  for (int d = 1; d < 64; d <<= 1) {
    int y = __shfl_up(x, d);
    if (lane >= d) x += y;
  }
  if (lane == 63) wsum[w] = x;
  __syncthreads();
  int woff = 0;
  #pragma unroll
  for (int j = 0; j < 4; ++j) if (j < w) woff += wsum[j];
  if (tid < SCAN_BLOCKS) boff[tid] = (x + woff) - v;
}

__global__ __launch_bounds__(256)
void scan_add_kernel(const int* __restrict__ boff, int* __restrict__ row_start) {
  int i = blockIdx.x * 256 + threadIdx.x;
  if (i < NNODES) row_start[i] += boff[blockIdx.x];
  if (i == 0) row_start[NNODES] = ETOT;
}

__global__ void scatter_kernel(const int* __restrict__ ei, const int* __restrict__ row_start,
                               int* __restrict__ cursor, int* __restrict__ col_src) {
  int e = blockIdx.x * 256 + threadIdx.x;
  if (e >= ETOT) return;
  int s, d;
  if (e < NEDGES) { s = ei[e]; d = ei[NEDGES + e]; }
  else { s = d = e - NEDGES; }
  int pos = atomicAdd(&cursor[d], 1);
  col_src[row_start[d] + pos] = s;
}

// ---------------- fp32 tiled GEMM (+ optional fp16 mirror of output) ----------------
__global__ __launch_bounds__(256)
void gemm_bias(const float* __restrict__ A, const float* __restrict__ B,
               const float* __restrict__ bias, float* __restrict__ Cout,
               __half* __restrict__ Chalf,
               int M, int K, int Ccols) {
  __shared__ float As[32][68];
  __shared__ float Bs[32][68];
  int row0 = blockIdx.x * 64, col0 = blockIdx.y * 64;
  int tid = threadIdx.x;
  int tx = tid & 15;
  int ty = tid >> 4;
  float acc[4][4] = {};
  for (int k0 = 0; k0 < K; k0 += 32) {
    #pragma unroll
    for (int i = 0; i < 8; ++i) {
      int idx = tid + i * 256;
      int r = idx >> 5, c = idx & 31;
      int gr = row0 + r;
      As[c][r] = (gr < M) ? A[(size_t)gr * K + k0 + c] : 0.f;
    }
    #pragma unroll
    for (int i = 0; i < 8; ++i) {
      int idx = tid + i * 256;
      int r = idx >> 6, c = idx & 63;
      Bs[r][c] = B[(size_t)(k0 + r) * Ccols + col0 + c];
    }
    __syncthreads();
    #pragma unroll
    for (int k = 0; k < 32; ++k) {
      float a4[4], b4[4];
      #pragma unroll
      for (int i = 0; i < 4; ++i) a4[i] = As[k][ty * 4 + i];
      #pragma unroll
      for (int j = 0; j < 4; ++j) b4[j] = Bs[k][tx * 4 + j];
      #pragma unroll
      for (int i = 0; i < 4; ++i)
        #pragma unroll
        for (int j = 0; j < 4; ++j)
          acc[i][j] = fmaf(a4[i], b4[j], acc[i][j]);
    }
    __syncthreads();
  }
  #pragma unroll
  for (int i = 0; i < 4; ++i) {
    int gr = row0 + ty * 4 + i;
    if (gr >= M) continue;
    float v[4];
    #pragma unroll
    for (int j = 0; j < 4; ++j) {
      int gc = col0 + tx * 4 + j;
      v[j] = acc[i][j] + (bias ? bias[gc] : 0.f);
      Cout[(size_t)gr * Ccols + gc] = v[j];
    }
    if (Chalf) {
      int gc0 = col0 + tx * 4;
      __half2* hp = (__half2*)(Chalf + (size_t)gr * Ccols + gc0);
      hp[0] = __floats2half2_rn(v[0], v[1]);
      hp[1] = __floats2half2_rn(v[2], v[3]);
    }
  }
}

// ---------------- per-node attention scores: sc_s/sc_d [N,4] (fp32 hproj) ----------------
__global__ __launch_bounds__(256)
void scores_kernel(const float* __restrict__ hproj,
                   const float* __restrict__ a_s, const float* __restrict__ a_d,
                   float* __restrict__ scs, float* __restrict__ scd) {
  int wave = threadIdx.x >> 6, lane = threadIdx.x & 63;
  int node = blockIdx.x * 4 + wave;
  if (node >= NNODES) return;
  float v0 = hproj[(size_t)node * 128 + lane];
  float v1 = hproj[(size_t)node * 128 + 64 + lane];
  float ps0 = v0 * a_s[lane],      ps1 = v1 * a_s[64 + lane];
  float pd0 = v0 * a_d[lane],      pd1 = v1 * a_d[64 + lane];
  #pragma unroll
  for (int d = 16; d >= 1; d >>= 1) {
    ps0 += __shfl_xor(ps0, d); ps1 += __shfl_xor(ps1, d);
    pd0 += __shfl_xor(pd0, d); pd1 += __shfl_xor(pd1, d);
  }
  if ((lane & 31) == 0) {
    int h0 = lane >> 5;
    scs[(size_t)node * 4 + h0]     = ps0;
    scs[(size_t)node * 4 + h0 + 2] = ps1;
    scd[(size_t)node * 4 + h0]     = pd0;
    scd[(size_t)node * 4 + h0 + 2] = pd1;
  }
}

// ---------------- fused GAT edge kernel (fp16 gather) ----------------
// Lane l's half2 covers flat channels {2l,2l+1} -> head = l>>4, ch pair (2l)&31.
// One 256B wave-load per edge covers all 4 heads x 32 channels.
__global__ __launch_bounds__(256)
void gat_edge_kernel(const __half2* __restrict__ hproj_h,
                     const float* __restrict__ scs, const float* __restrict__ scd,
                     const int* __restrict__ row_start, const int* __restrict__ col_src,
                     const float* __restrict__ bias, float* __restrict__ hout) {
  int wave = threadIdx.x >> 6, lane = threadIdx.x & 63;
  int node = blockIdx.x * 4 + wave;
  if (node >= NNODES) return;
  int s = row_start[node], e = row_start[node + 1];
  float4 sd = *(const float4*)(scd + (size_t)node * 4);

  // pass 1: per-head segment max (lanes = edges)
  float m0 = -INFINITY, m1 = -INFINITY, m2 = -INFINITY, m3 = -INFINITY;
  for (int i = s + lane; i < e; i += 64) {
    int src = col_src[i];
    float4 ss = *(const float4*)(scs + (size_t)src * 4);
    m0 = fmaxf(m0, lrelu(ss.x + sd.x));
    m1 = fmaxf(m1, lrelu(ss.y + sd.y));
    m2 = fmaxf(m2, lrelu(ss.z + sd.z));
    m3 = fmaxf(m3, lrelu(ss.w + sd.w));
  }
  #pragma unroll
  for (int d = 32; d >= 1; d >>= 1) {
    m0 = fmaxf(m0, __shfl_xor(m0, d));
    m1 = fmaxf(m1, __shfl_xor(m1, d));
    m2 = fmaxf(m2, __shfl_xor(m2, d));
    m3 = fmaxf(m3, __shfl_xor(m3, d));
  }

  int h = lane >> 4;                    // this lane's head
  float den0 = 0, den1 = 0, den2 = 0, den3 = 0;
  float accx = 0.f, accy = 0.f;
  for (int base = s; base < e; base += 64) {
    int i = base + lane;
    int cnt = min(64, e - base);
    int srcReg = 0;
    float a0 = 0, a1 = 0, a2 = 0, a3 = 0;
    if (i < e) {
      srcReg = col_src[i];
      float4 ss = *(const float4*)(scs + (size_t)srcReg * 4);
      a0 = __expf(lrelu(ss.x + sd.x) - m0);
      a1 = __expf(lrelu(ss.y + sd.y) - m1);
      a2 = __expf(lrelu(ss.z + sd.z) - m2);
      a3 = __expf(lrelu(ss.w + sd.w) - m3);
      den0 += a0; den1 += a1; den2 += a2; den3 += a3;
    }
    for (int j = 0; j < cnt; ++j) {
      int src  = __shfl(srcReg, j);
      float t0 = __shfl(a0, j), t1 = __shfl(a1, j);
      float t2 = __shfl(a2, j), t3 = __shfl(a3, j);
      float th = (h == 0) ? t0 : (h == 1) ? t1 : (h == 2) ? t2 : t3;
      float2 hv = __half22float2(hproj_h[(size_t)src * 64 + lane]);
      accx = fmaf(th, hv.x, accx);
      accy = fmaf(th, hv.y, accy);
    }
  }
  #pragma unroll
  for (int d = 32; d >= 1; d >>= 1) {
    den0 += __shfl_xor(den0, d);
    den1 += __shfl_xor(den1, d);
    den2 += __shfl_xor(den2, d);
    den3 += __shfl_xor(den3, d);
  }
  float den = (h == 0) ? den0 : (h == 1) ? den1 : (h == 2) ? den2 : den3;
  float rden = 1.f / fmaxf(den, 1e-16f);
  float vx = accx * rden, vy = accy * rden;
  vx += __shfl_xor(vx, 16); vy += __shfl_xor(vy, 16);   // heads differ in lane bits 4,5
  vx += __shfl_xor(vx, 32); vy += __shfl_xor(vy, 32);
  if (lane < 16) {
    int c0 = 2 * lane;
    float v0 = vx * 0.25f + bias[c0];
    float v1 = vy * 0.25f + bias[c0 + 1];
    float2 o;
    o.x = v0 > 0.f ? v0 : expm1f(v0);
    o.y = v1 > 0.f ? v1 : expm1f(v1);
    *(float2*)(hout + (size_t)node * 32 + c0) = o;
  }
}

// ---------------- hierarchical global mean pool ----------------
#define POOL_BLOCKS 128
__global__ __launch_bounds__(256)
void pool_kernel(const float* __restrict__ h, const int* __restrict__ batch,
                 float* __restrict__ pooled, float* __restrict__ cnt) {
  __shared__ float acc[NGRAPH][HIDC];
  __shared__ float ccnt[NGRAPH];
  int tid = threadIdx.x;
  const int chunk = (NNODES + POOL_BLOCKS - 1) / POOL_BLOCKS;
  int n0 = blockIdx.x * chunk;
  int n1 = min(n0 + chunk, NNODES);
  if (n0 >= NNODES) return;
  int g0 = batch[n0], g1 = batch[n1 - 1];
  int rows = g1 - g0 + 1;
  for (int idx = tid; idx < rows * HIDC; idx += 256)
    acc[g0 + (idx >> 5)][idx & 31] = 0.f;
  for (int g = tid; g < rows; g += 256) ccnt[g0 + g] = 0.f;
  __syncthreads();
  int c = tid & 31;
  for (int node = n0 + (tid >> 5); node < n1; node += 8) {
    int g = batch[node];
    atomicAdd(&acc[g][c], h[(size_t)node * HIDC + c]);
    if (c == 0) atomicAdd(&ccnt[g], 1.f);
  }
  __syncthreads();
  for (int idx = tid; idx < rows * HIDC; idx += 256) {
    int g = g0 + (idx >> 5), cc = idx & 31;
    atomicAdd(&pooled[g * HIDC + cc], acc[g][cc]);
  }
  for (int g = tid; g < rows; g += 256) atomicAdd(&cnt[g0 + g], ccnt[g0 + g]);
}

__global__ void final_kernel(const float* __restrict__ pooled, const float* __restrict__ cnt,
                             const float* __restrict__ w, const float* __restrict__ b,
                             float* __restrict__ out) {
  int t = threadIdx.x;
  if (t >= NGRAPH * NCLS) return;
  int g = t / NCLS, j = t - g * NCLS;
  float inv = 1.f / fmaxf(cnt[g], 1.f);
  float acc = 0.f;
  #pragma unroll
  for (int c = 0; c < HIDC; ++c)
    acc = fmaf(pooled[g * HIDC + c], w[c * NCLS + j], acc);
  out[t] = acc * inv + b[j];
}

extern "C" void kernel_launch(void* const* d_in, const int* in_sizes, int n_in,
                              void* d_out, int out_size, void* d_ws, size_t ws_size,
                              hipStream_t stream) {
  const float* x      = (const float*)d_in[0];
  const int*   ei     = (const int*)d_in[1];
  const int*   batch  = (const int*)d_in[2];
  const float* enc1_w = (const float*)d_in[3];
  const float* enc1_b = (const float*)d_in[4];
  const float* enc2_w = (const float*)d_in[5];
  const float* enc2_b = (const float*)d_in[6];
  const float* lin1_w = (const float*)d_in[7];
  const float* lin1_b = (const float*)d_in[8];
  const float* gw[4]  = {(const float*)d_in[9],  (const float*)d_in[13], (const float*)d_in[17], (const float*)d_in[21]};
  const float* gas[4] = {(const float*)d_in[10], (const float*)d_in[14], (const float*)d_in[18], (const float*)d_in[22]};
  const float* gad[4] = {(const float*)d_in[11], (const float*)d_in[15], (const float*)d_in[19], (const float*)d_in[23]};
  const float* gb[4]  = {(const float*)d_in[12], (const float*)d_in[16], (const float*)d_in[20], (const float*)d_in[24]};
  float* out = (float*)d_out;

  float* fws    = (float*)d_ws;
  float* hproj  = fws;
  float* hbig   = hproj  + (size_t)NNODES * 128;
  float* hsmall = hbig   + (size_t)NNODES * 256;
  float* scs    = hsmall + (size_t)NNODES * 32;
  float* scd    = scs    + (size_t)NNODES * 4;
  float* pooled = scd    + (size_t)NNODES * 4;
  float* cnt    = pooled + NGRAPH * HIDC;
  int*   deg    = (int*)(cnt + NGRAPH);
  int*   row_start = deg + NNODES;
  int*   col_src   = row_start + NNODES + 1;
  int*   bsum      = col_src + ETOT;
  int*   boff      = bsum + SCAN_BLOCKS;
  __half* hproj_h  = (__half*)(boff + SCAN_BLOCKS);   // N*128 fp16 (12.8 MB)

  // --- CSR build (parallel scan) ---
  hipMemsetAsync(deg, 0, NNODES * sizeof(int), stream);
  hist_kernel<<<(ETOT + 255) / 256, 256, 0, stream>>>(ei, deg);
  scan_block_kernel<<<SCAN_BLOCKS, 256, 0, stream>>>(deg, row_start, bsum);
  scan_sums_kernel<<<1, 256, 0, stream>>>(bsum, boff);
  scan_add_kernel<<<SCAN_BLOCKS, 256, 0, stream>>>(boff, row_start);
  hipMemsetAsync(deg, 0, NNODES * sizeof(int), stream);
  scatter_kernel<<<(ETOT + 255) / 256, 256, 0, stream>>>(ei, row_start, deg, col_src);

  dim3 g128((NNODES + 63) / 64, 2), g256((NNODES + 63) / 64, 4);

  gemm_bias<<<g128, 256, 0, stream>>>(x,     enc1_w, enc1_b, hproj, nullptr, NNODES, 128, 128);
  gemm_bias<<<g256, 256, 0, stream>>>(hproj, enc2_w, enc2_b, hbig,  nullptr, NNODES, 128, 256);

  const float* cur = hbig; int curK = 256;
  for (int L = 0; L < 4; ++L) {
    gemm_bias<<<g128, 256, 0, stream>>>(cur, gw[L], nullptr, hproj, hproj_h, NNODES, curK, 128);
    scores_kernel<<<(NNODES + 3) / 4, 256, 0, stream>>>(hproj, gas[L], gad[L], scs, scd);
    gat_edge_kernel<<<(NNODES + 3) / 4, 256, 0, stream>>>((const __half2*)hproj_h, scs, scd, row_start, col_src, gb[L], hsmall);
    cur = hsmall; curK = 32;
  }

  hipMemsetAsync(pooled, 0, (NGRAPH * HIDC + NGRAPH) * sizeof(float), stream);
  pool_kernel<<<POOL_BLOCKS, 256, 0, stream>>>(hsmall, batch, pooled, cnt);
  final_kernel<<<1, 640, 0, stream>>>(pooled, cnt, lin1_w, lin1_b, out);
}

// Round 5
// 674.870 us; speedup vs baseline: 1.0759x; 1.0759x over previous
//
#include <hip/hip_runtime.h>
#include <hip/hip_fp16.h>
#include <math.h>

#define NNODES 50000
#define NEDGES 800000
#define ETOT   (NEDGES + NNODES)
#define HIDC   32
#define NGRAPH 64
#define NCLS   10
#define SLOPE  0.2f
#define SCAN_BLOCKS ((NNODES + 255) / 256)   // 196

__device__ __forceinline__ float lrelu(float v) { return v > 0.f ? v : SLOPE * v; }

// ---------------- CSR build (by dst), includes self loops ----------------
__global__ void hist_kernel(const int* __restrict__ ei, int* __restrict__ deg) {
  int e = blockIdx.x * 256 + threadIdx.x;
  if (e >= ETOT) return;
  int d = (e < NEDGES) ? ei[NEDGES + e] : (e - NEDGES);
  atomicAdd(&deg[d], 1);
}

__global__ __launch_bounds__(256)
void scan_block_kernel(const int* __restrict__ deg, int* __restrict__ row_start,
                       int* __restrict__ bsum) {
  __shared__ int wsum[4];
  int i = blockIdx.x * 256 + threadIdx.x;
  int v = (i < NNODES) ? deg[i] : 0;
  int lane = threadIdx.x & 63, w = threadIdx.x >> 6;
  int x = v;
  #pragma unroll
  for (int d = 1; d < 64; d <<= 1) {
    int y = __shfl_up(x, d);
    if (lane >= d) x += y;
  }
  if (lane == 63) wsum[w] = x;
  __syncthreads();
  int woff = 0;
  #pragma unroll
  for (int j = 0; j < 4; ++j) if (j < w) woff += wsum[j];
  int incl = x + woff;
  if (i < NNODES) row_start[i] = incl - v;
  if (threadIdx.x == 255) bsum[blockIdx.x] = incl;
}

__global__ __launch_bounds__(256)
void scan_sums_kernel(const int* __restrict__ bsum, int* __restrict__ boff) {
  __shared__ int wsum[4];
  int tid = threadIdx.x;
  int v = (tid < SCAN_BLOCKS) ? bsum[tid] : 0;
  int lane = tid & 63, w = tid >> 6;
  int x = v;
  #pragma unroll
  for (int d = 1; d < 64; d <<= 1) {
    int y = __shfl_up(x, d);
    if (lane >= d) x += y;
  }
  if (lane == 63) wsum[w] = x;
  __syncthreads();
  int woff = 0;
  #pragma unroll
  for (int j = 0; j < 4; ++j) if (j < w) woff += wsum[j];
  if (tid < SCAN_BLOCKS) boff[tid] = (x + woff) - v;
}

__global__ __launch_bounds__(256)
void scan_add_kernel(const int* __restrict__ boff, int* __restrict__ row_start) {
  int i = blockIdx.x * 256 + threadIdx.x;
  if (i < NNODES) row_start[i] += boff[blockIdx.x];
  if (i == 0) row_start[NNODES] = ETOT;
}

__global__ void scatter_kernel(const int* __restrict__ ei, const int* __restrict__ row_start,
                               int* __restrict__ cursor, int* __restrict__ col_src) {
  int e = blockIdx.x * 256 + threadIdx.x;
  if (e >= ETOT) return;
  int s, d;
  if (e < NEDGES) { s = ei[e]; d = ei[NEDGES + e]; }
  else { s = d = e - NEDGES; }
  int pos = atomicAdd(&cursor[d], 1);
  col_src[row_start[d] + pos] = s;
}

// ---------------- fp32 tiled GEMM (+ optional fp16 mirror of output) ----------------
__global__ __launch_bounds__(256)
void gemm_bias(const float* __restrict__ A, const float* __restrict__ B,
               const float* __restrict__ bias, float* __restrict__ Cout,
               __half* __restrict__ Chalf,
               int M, int K, int Ccols) {
  __shared__ float As[32][68];
  __shared__ float Bs[32][68];
  int row0 = blockIdx.x * 64, col0 = blockIdx.y * 64;
  int tid = threadIdx.x;
  int tx = tid & 15;
  int ty = tid >> 4;
  float acc[4][4] = {};
  for (int k0 = 0; k0 < K; k0 += 32) {
    #pragma unroll
    for (int i = 0; i < 8; ++i) {
      int idx = tid + i * 256;
      int r = idx >> 5, c = idx & 31;
      int gr = row0 + r;
      As[c][r] = (gr < M) ? A[(size_t)gr * K + k0 + c] : 0.f;
    }
    #pragma unroll
    for (int i = 0; i < 8; ++i) {
      int idx = tid + i * 256;
      int r = idx >> 6, c = idx & 63;
      Bs[r][c] = B[(size_t)(k0 + r) * Ccols + col0 + c];
    }
    __syncthreads();
    #pragma unroll
    for (int k = 0; k < 32; ++k) {
      float a4[4], b4[4];
      #pragma unroll
      for (int i = 0; i < 4; ++i) a4[i] = As[k][ty * 4 + i];
      #pragma unroll
      for (int j = 0; j < 4; ++j) b4[j] = Bs[k][tx * 4 + j];
      #pragma unroll
      for (int i = 0; i < 4; ++i)
        #pragma unroll
        for (int j = 0; j < 4; ++j)
          acc[i][j] = fmaf(a4[i], b4[j], acc[i][j]);
    }
    __syncthreads();
  }
  #pragma unroll
  for (int i = 0; i < 4; ++i) {
    int gr = row0 + ty * 4 + i;
    if (gr >= M) continue;
    float v[4];
    #pragma unroll
    for (int j = 0; j < 4; ++j) {
      int gc = col0 + tx * 4 + j;
      v[j] = acc[i][j] + (bias ? bias[gc] : 0.f);
      Cout[(size_t)gr * Ccols + gc] = v[j];
    }
    if (Chalf) {
      int gc0 = col0 + tx * 4;
      __half2* hp = (__half2*)(Chalf + (size_t)gr * Ccols + gc0);
      hp[0] = __floats2half2_rn(v[0], v[1]);
      hp[1] = __floats2half2_rn(v[2], v[3]);
    }
  }
}

// ---------------- per-node attention scores: sc_s/sc_d [N,4] ----------------
__global__ __launch_bounds__(256)
void scores_kernel(const float* __restrict__ hproj,
                   const float* __restrict__ a_s, const float* __restrict__ a_d,
                   float* __restrict__ scs, float* __restrict__ scd) {
  int wave = threadIdx.x >> 6, lane = threadIdx.x & 63;
  int node = blockIdx.x * 4 + wave;
  if (node >= NNODES) return;
  float v0 = hproj[(size_t)node * 128 + lane];
  float v1 = hproj[(size_t)node * 128 + 64 + lane];
  float ps0 = v0 * a_s[lane],      ps1 = v1 * a_s[64 + lane];
  float pd0 = v0 * a_d[lane],      pd1 = v1 * a_d[64 + lane];
  #pragma unroll
  for (int d = 16; d >= 1; d >>= 1) {
    ps0 += __shfl_xor(ps0, d); ps1 += __shfl_xor(ps1, d);
    pd0 += __shfl_xor(pd0, d); pd1 += __shfl_xor(pd1, d);
  }
  if ((lane & 31) == 0) {
    int h0 = lane >> 5;
    scs[(size_t)node * 4 + h0]     = ps0;
    scs[(size_t)node * 4 + h0 + 2] = ps1;
    scd[(size_t)node * 4 + h0]     = pd0;
    scd[(size_t)node * 4 + h0 + 2] = pd1;
  }
}

// ---------------- fused GAT edge kernel (LDS-staged alphas, 16 lanes/edge) ----------------
// Fast path (deg<=64): one scs gather; alphas+src staged in wave-private LDS;
// heavy loop does 4 edges/iter, each 16-lane group loads one contiguous 256B
// fp16 row slice (dwordx4/lane) -> no per-edge shuffles, independent iters.
__global__ __launch_bounds__(256)
void gat_edge_kernel(const __half2* __restrict__ hproj_h,
                     const float* __restrict__ scs, const float* __restrict__ scd,
                     const int* __restrict__ row_start, const int* __restrict__ col_src,
                     const float* __restrict__ bias, float* __restrict__ hout) {
  __shared__ int src_sh[4][64];
  __shared__ __align__(16) float al_sh[4][256];
  int wave = threadIdx.x >> 6, lane = threadIdx.x & 63;
  int node = blockIdx.x * 4 + wave;
  if (node >= NNODES) return;
  int s = row_start[node], e = row_start[node + 1];
  int deg = e - s;
  float4 sd = *(const float4*)(scd + (size_t)node * 4);
  const uint4* hp4 = (const uint4*)hproj_h;   // 16 x uint4 per node row (128 fp16)

  if (deg <= 64) {
    // ---- scores, max, alphas (lane = edge), all in registers ----
    int i = s + lane;
    bool valid = i < e;
    int srcv = 0;
    float4 ss = make_float4(0.f, 0.f, 0.f, 0.f);
    if (valid) {
      srcv = col_src[i];
      ss = *(const float4*)(scs + (size_t)srcv * 4);
    }
    float e0 = lrelu(ss.x + sd.x), e1 = lrelu(ss.y + sd.y);
    float e2 = lrelu(ss.z + sd.z), e3 = lrelu(ss.w + sd.w);
    float m0 = valid ? e0 : -INFINITY, m1 = valid ? e1 : -INFINITY;
    float m2 = valid ? e2 : -INFINITY, m3 = valid ? e3 : -INFINITY;
    #pragma unroll
    for (int d = 32; d >= 1; d >>= 1) {
      m0 = fmaxf(m0, __shfl_xor(m0, d));
      m1 = fmaxf(m1, __shfl_xor(m1, d));
      m2 = fmaxf(m2, __shfl_xor(m2, d));
      m3 = fmaxf(m3, __shfl_xor(m3, d));
    }
    float a0 = valid ? __expf(e0 - m0) : 0.f;
    float a1 = valid ? __expf(e1 - m1) : 0.f;
    float a2 = valid ? __expf(e2 - m2) : 0.f;
    float a3 = valid ? __expf(e3 - m3) : 0.f;
    float d0 = a0, d1 = a1, d2 = a2, d3 = a3;
    #pragma unroll
    for (int d = 32; d >= 1; d >>= 1) {
      d0 += __shfl_xor(d0, d);
      d1 += __shfl_xor(d1, d);
      d2 += __shfl_xor(d2, d);
      d3 += __shfl_xor(d3, d);
    }
    // ---- stage to wave-private LDS (invalid lanes stage zeros) ----
    src_sh[wave][lane] = srcv;
    *(float4*)&al_sh[wave][lane * 4] = make_float4(a0, a1, a2, a3);

    // ---- heavy loop: 4 edges per iteration ----
    int g = lane >> 4;        // edge-in-group
    int r = lane & 15;        // payload slot: channels [8r, 8r+8), head = r>>2
    int head = r >> 2;
    float acc[8] = {};
    int ng = (deg + 3) >> 2;
    for (int jg = 0; jg < ng; ++jg) {
      int j = jg * 4 + g;
      int src = src_sh[wave][j];
      float al = al_sh[wave][j * 4 + head];
      uint4 p = hp4[(size_t)src * 16 + r];
      float2 f0 = __half22float2(*(__half2*)&p.x);
      float2 f1 = __half22float2(*(__half2*)&p.y);
      float2 f2 = __half22float2(*(__half2*)&p.z);
      float2 f3 = __half22float2(*(__half2*)&p.w);
      acc[0] = fmaf(al, f0.x, acc[0]); acc[1] = fmaf(al, f0.y, acc[1]);
      acc[2] = fmaf(al, f1.x, acc[2]); acc[3] = fmaf(al, f1.y, acc[3]);
      acc[4] = fmaf(al, f2.x, acc[4]); acc[5] = fmaf(al, f2.y, acc[5]);
      acc[6] = fmaf(al, f3.x, acc[6]); acc[7] = fmaf(al, f3.y, acc[7]);
    }
    // ---- normalize, reduce groups (xor 16,32) and heads (xor 4,8) ----
    float den = (head == 0) ? d0 : (head == 1) ? d1 : (head == 2) ? d2 : d3;
    float rd = 1.f / fmaxf(den, 1e-16f);
    #pragma unroll
    for (int k = 0; k < 8; ++k) acc[k] *= rd;
    #pragma unroll
    for (int d = 4; d <= 32; d <<= 1) {
      #pragma unroll
      for (int k = 0; k < 8; ++k) acc[k] += __shfl_xor(acc[k], d);
    }
    if (lane < 4) {
      float o[8];
      #pragma unroll
      for (int k = 0; k < 8; ++k) {
        float v = acc[k] * 0.25f + bias[8 * lane + k];
        o[k] = v > 0.f ? v : expm1f(v);
      }
      float* op = hout + (size_t)node * 32 + 8 * lane;
      *(float4*)op       = make_float4(o[0], o[1], o[2], o[3]);
      *(float4*)(op + 4) = make_float4(o[4], o[5], o[6], o[7]);
    }
  } else {
    // ---- generic slow path (deg > 64): R4 structure ----
    float m0 = -INFINITY, m1 = -INFINITY, m2 = -INFINITY, m3 = -INFINITY;
    for (int i = s + lane; i < e; i += 64) {
      int src = col_src[i];
      float4 ss = *(const float4*)(scs + (size_t)src * 4);
      m0 = fmaxf(m0, lrelu(ss.x + sd.x));
      m1 = fmaxf(m1, lrelu(ss.y + sd.y));
      m2 = fmaxf(m2, lrelu(ss.z + sd.z));
      m3 = fmaxf(m3, lrelu(ss.w + sd.w));
    }
    #pragma unroll
    for (int d = 32; d >= 1; d >>= 1) {
      m0 = fmaxf(m0, __shfl_xor(m0, d));
      m1 = fmaxf(m1, __shfl_xor(m1, d));
      m2 = fmaxf(m2, __shfl_xor(m2, d));
      m3 = fmaxf(m3, __shfl_xor(m3, d));
    }
    int g = lane >> 4, r = lane & 15, head = r >> 2;
    float den0 = 0, den1 = 0, den2 = 0, den3 = 0;
    float acc[8] = {};
    for (int base = s; base < e; base += 64) {
      int i = base + lane;
      bool valid = i < e;
      int srcv = 0;
      float a0 = 0, a1 = 0, a2 = 0, a3 = 0;
      if (valid) {
        srcv = col_src[i];
        float4 ss = *(const float4*)(scs + (size_t)srcv * 4);
        a0 = __expf(lrelu(ss.x + sd.x) - m0);
        a1 = __expf(lrelu(ss.y + sd.y) - m1);
        a2 = __expf(lrelu(ss.z + sd.z) - m2);
        a3 = __expf(lrelu(ss.w + sd.w) - m3);
        den0 += a0; den1 += a1; den2 += a2; den3 += a3;
      }
      src_sh[wave][lane] = srcv;
      *(float4*)&al_sh[wave][lane * 4] = make_float4(a0, a1, a2, a3);
      int cnt = min(64, e - base);
      int ngc = (cnt + 3) >> 2;
      for (int jg = 0; jg < ngc; ++jg) {
        int j = jg * 4 + g;
        int src = src_sh[wave][j];
        float al = al_sh[wave][j * 4 + head];
        uint4 p = hp4[(size_t)src * 16 + r];
        float2 f0 = __half22float2(*(__half2*)&p.x);
        float2 f1 = __half22float2(*(__half2*)&p.y);
        float2 f2 = __half22float2(*(__half2*)&p.z);
        float2 f3 = __half22float2(*(__half2*)&p.w);
        acc[0] = fmaf(al, f0.x, acc[0]); acc[1] = fmaf(al, f0.y, acc[1]);
        acc[2] = fmaf(al, f1.x, acc[2]); acc[3] = fmaf(al, f1.y, acc[3]);
        acc[4] = fmaf(al, f2.x, acc[4]); acc[5] = fmaf(al, f2.y, acc[5]);
        acc[6] = fmaf(al, f3.x, acc[6]); acc[7] = fmaf(al, f3.y, acc[7]);
      }
    }
    #pragma unroll
    for (int d = 32; d >= 1; d >>= 1) {
      den0 += __shfl_xor(den0, d);
      den1 += __shfl_xor(den1, d);
      den2 += __shfl_xor(den2, d);
      den3 += __shfl_xor(den3, d);
    }
    float den = (head == 0) ? den0 : (head == 1) ? den1 : (head == 2) ? den2 : den3;
    float rd = 1.f / fmaxf(den, 1e-16f);
    #pragma unroll
    for (int k = 0; k < 8; ++k) acc[k] *= rd;
    #pragma unroll
    for (int d = 4; d <= 32; d <<= 1) {
      #pragma unroll
      for (int k = 0; k < 8; ++k) acc[k] += __shfl_xor(acc[k], d);
    }
    if (lane < 4) {
      float o[8];
      #pragma unroll
      for (int k = 0; k < 8; ++k) {
        float v = acc[k] * 0.25f + bias[8 * lane + k];
        o[k] = v > 0.f ? v : expm1f(v);
      }
      float* op = hout + (size_t)node * 32 + 8 * lane;
      *(float4*)op       = make_float4(o[0], o[1], o[2], o[3]);
      *(float4*)(op + 4) = make_float4(o[4], o[5], o[6], o[7]);
    }
  }
}

// ---------------- hierarchical global mean pool ----------------
#define POOL_BLOCKS 128
__global__ __launch_bounds__(256)
void pool_kernel(const float* __restrict__ h, const int* __restrict__ batch,
                 float* __restrict__ pooled, float* __restrict__ cnt) {
  __shared__ float acc[NGRAPH][HIDC];
  __shared__ float ccnt[NGRAPH];
  int tid = threadIdx.x;
  const int chunk = (NNODES + POOL_BLOCKS - 1) / POOL_BLOCKS;
  int n0 = blockIdx.x * chunk;
  int n1 = min(n0 + chunk, NNODES);
  if (n0 >= NNODES) return;
  int g0 = batch[n0], g1 = batch[n1 - 1];
  int rows = g1 - g0 + 1;
  for (int idx = tid; idx < rows * HIDC; idx += 256)
    acc[g0 + (idx >> 5)][idx & 31] = 0.f;
  for (int g = tid; g < rows; g += 256) ccnt[g0 + g] = 0.f;
  __syncthreads();
  int c = tid & 31;
  for (int node = n0 + (tid >> 5); node < n1; node += 8) {
    int g = batch[node];
    atomicAdd(&acc[g][c], h[(size_t)node * HIDC + c]);
    if (c == 0) atomicAdd(&ccnt[g], 1.f);
  }
  __syncthreads();
  for (int idx = tid; idx < rows * HIDC; idx += 256) {
    int g = g0 + (idx >> 5), cc = idx & 31;
    atomicAdd(&pooled[g * HIDC + cc], acc[g][cc]);
  }
  for (int g = tid; g < rows; g += 256) atomicAdd(&cnt[g0 + g], ccnt[g0 + g]);
}

__global__ void final_kernel(const float* __restrict__ pooled, const float* __restrict__ cnt,
                             const float* __restrict__ w, const float* __restrict__ b,
                             float* __restrict__ out) {
  int t = threadIdx.x;
  if (t >= NGRAPH * NCLS) return;
  int g = t / NCLS, j = t - g * NCLS;
  float inv = 1.f / fmaxf(cnt[g], 1.f);
  float acc = 0.f;
  #pragma unroll
  for (int c = 0; c < HIDC; ++c)
    acc = fmaf(pooled[g * HIDC + c], w[c * NCLS + j], acc);
  out[t] = acc * inv + b[j];
}

extern "C" void kernel_launch(void* const* d_in, const int* in_sizes, int n_in,
                              void* d_out, int out_size, void* d_ws, size_t ws_size,
                              hipStream_t stream) {
  const float* x      = (const float*)d_in[0];
  const int*   ei     = (const int*)d_in[1];
  const int*   batch  = (const int*)d_in[2];
  const float* enc1_w = (const float*)d_in[3];
  const float* enc1_b = (const float*)d_in[4];
  const float* enc2_w = (const float*)d_in[5];
  const float* enc2_b = (const float*)d_in[6];
  const float* lin1_w = (const float*)d_in[7];
  const float* lin1_b = (const float*)d_in[8];
  const float* gw[4]  = {(const float*)d_in[9],  (const float*)d_in[13], (const float*)d_in[17], (const float*)d_in[21]};
  const float* gas[4] = {(const float*)d_in[10], (const float*)d_in[14], (const float*)d_in[18], (const float*)d_in[22]};
  const float* gad[4] = {(const float*)d_in[11], (const float*)d_in[15], (const float*)d_in[19], (const float*)d_in[23]};
  const float* gb[4]  = {(const float*)d_in[12], (const float*)d_in[16], (const float*)d_in[20], (const float*)d_in[24]};
  float* out = (float*)d_out;

  float* fws    = (float*)d_ws;
  float* hproj  = fws;
  float* hbig   = hproj  + (size_t)NNODES * 128;
  float* hsmall = hbig   + (size_t)NNODES * 256;
  float* scs    = hsmall + (size_t)NNODES * 32;
  float* scd    = scs    + (size_t)NNODES * 4;
  float* pooled = scd    + (size_t)NNODES * 4;
  float* cnt    = pooled + NGRAPH * HIDC;
  int*   deg    = (int*)(cnt + NGRAPH);
  int*   row_start = deg + NNODES;
  int*   col_src   = row_start + NNODES + 1;
  int*   bsum      = col_src + ETOT;
  int*   boff      = bsum + SCAN_BLOCKS;
  __half* hproj_h  = (__half*)(boff + SCAN_BLOCKS);   // N*128 fp16 (12.8 MB)

  // --- CSR build (parallel scan) ---
  hipMemsetAsync(deg, 0, NNODES * sizeof(int), stream);
  hist_kernel<<<(ETOT + 255) / 256, 256, 0, stream>>>(ei, deg);
  scan_block_kernel<<<SCAN_BLOCKS, 256, 0, stream>>>(deg, row_start, bsum);
  scan_sums_kernel<<<1, 256, 0, stream>>>(bsum, boff);
  scan_add_kernel<<<SCAN_BLOCKS, 256, 0, stream>>>(boff, row_start);
  hipMemsetAsync(deg, 0, NNODES * sizeof(int), stream);
  scatter_kernel<<<(ETOT + 255) / 256, 256, 0, stream>>>(ei, row_start, deg, col_src);

  dim3 g128((NNODES + 63) / 64, 2), g256((NNODES + 63) / 64, 4);

  gemm_bias<<<g128, 256, 0, stream>>>(x,     enc1_w, enc1_b, hproj, nullptr, NNODES, 128, 128);
  gemm_bias<<<g256, 256, 0, stream>>>(hproj, enc2_w, enc2_b, hbig,  nullptr, NNODES, 128, 256);

  const float* cur = hbig; int curK = 256;
  for (int L = 0; L < 4; ++L) {
    gemm_bias<<<g128, 256, 0, stream>>>(cur, gw[L], nullptr, hproj, hproj_h, NNODES, curK, 128);
    scores_kernel<<<(NNODES + 3) / 4, 256, 0, stream>>>(hproj, gas[L], gad[L], scs, scd);
    gat_edge_kernel<<<(NNODES + 3) / 4, 256, 0, stream>>>((const __half2*)hproj_h, scs, scd, row_start, col_src, gb[L], hsmall);
    cur = hsmall; curK = 32;
  }

  hipMemsetAsync(pooled, 0, (NGRAPH * HIDC + NGRAPH) * sizeof(float), stream);
  pool_kernel<<<POOL_BLOCKS, 256, 0, stream>>>(hsmall, batch, pooled, cnt);
  final_kernel<<<1, 640, 0, stream>>>(pooled, cnt, lin1_w, lin1_b, out);
}